// Round 6
// baseline (206.336 us; speedup 1.0000x reference)
//
#include <hip/hip_runtime.h>
#include <hip/hip_bf16.h>
#include <math.h>

#define Wd 8192
#define Bd 32
#define Ttile 64

// ws layout (float offsets)
#define OFF_G    0                          // (unused by kernels now, kept)
#define OFF_H    192                        // 3
#define OFF_BASE 195                        // 1
#define OFF_XSEQ 256                        // 32*8192
#define OFF_PART (256 + Bd*Wd)              // [b][32 tile-groups][640]
#define OFF_S    (OFF_PART + Bd*32*640)     // 32*640
#define OFF_M    (OFF_S + Bd*640)           // 32*3
#define OFF_E    (OFF_M + 96)               // 32*64
#define OFF_F    (OFF_E + Bd*64)            // 32*64
#define OFF_FRAG (OFF_F + Bd*64)            // 2 ver * 9 nt * 2 kb * 64 lane * uint4

typedef __attribute__((ext_vector_type(8))) short bf16x8;
typedef __attribute__((ext_vector_type(4))) float f32x4;

__device__ __forceinline__ unsigned short f2bf(float v) {
    return __builtin_bit_cast(unsigned short, __float2bfloat16(v));
}
__device__ __forceinline__ float bf2f(unsigned short h) {
    return __builtin_bit_cast(float, (unsigned)h << 16);
}
__device__ __forceinline__ unsigned pk2(float v0, float v1) {
    return (unsigned)f2bf(v0) | ((unsigned)f2bf(v1) << 16);
}

// ---------------- k0: fold sp_w through dwconv(V)+qkv into g/h/base; pack
// hi/lo bf16 B-fragments (col = weight-row, k = channel) of the 131x64 matrix.
__global__ __launch_bounds__(256) void k0_setup(const float* __restrict__ qkv_w,
                         const float* __restrict__ qkv_b,
                         const float* __restrict__ dw_w, const float* __restrict__ dw_b,
                         const float* __restrict__ sp_w, const float* __restrict__ sp_b,
                         float* __restrict__ ws)
{
    __shared__ float sw[64*64];   // qkv_w rows 128..191: sw[c*64+ch]
    __shared__ float sdw[192];    // dw_w[(128+c)*9+3+j] -> sdw[c*3+j]
    __shared__ float ssp[64];
    __shared__ float sqb[64];     // qkv_b[128+c]
    __shared__ float sdb[64];     // dw_b[128+c]
    __shared__ float sG[192];     // G[j*64+ch]
    int tid = threadIdx.x;
    for (int i = tid; i < 4096; i += 256) sw[i] = qkv_w[128*64 + i];
    if (tid < 192) { int c = tid/3, j = tid - 3*c; sdw[tid] = dw_w[(128+c)*9 + 3 + j]; }
    if (tid < 64)  { ssp[tid] = sp_w[tid]; sqb[tid] = qkv_b[128+tid]; sdb[tid] = dw_b[128+tid]; }
    __syncthreads();
    if (tid < 192) {
        int j = tid >> 6, ch = tid & 63;
        float acc = 0.f;
        #pragma unroll 8
        for (int c = 0; c < 64; c++)
            acc += ssp[c] * sdw[c*3+j] * sw[c*64 + ch];
        sG[j*64 + ch] = acc;
    } else if (tid < 195) {
        int j = tid - 192;
        float h = 0.f;
        #pragma unroll 8
        for (int c = 0; c < 64; c++)
            h += ssp[c] * sdw[c*3+j] * sqb[c];
        ws[OFF_H + j] = h;
    } else if (tid == 195) {
        float base = sp_b[0];
        #pragma unroll 8
        for (int c = 0; c < 64; c++) base += ssp[c] * sdb[c];
        ws[OFF_BASE] = base;
    }
    __syncthreads();
    // pack fragments: item = (ver, nt, kb, lane); row = nt*16+(l&15), k = kb*32+(l>>4)*8+e
    for (int it = tid; it < 36*64; it += 256) {
        int lane = it & 63;
        int cidx = it >> 6;          // 0..35
        int ver = cidx / 18;
        int rem = cidx - ver*18;
        int nt = rem >> 1, kb = rem & 1;
        int row = nt*16 + (lane & 15);
        int ks  = kb*32 + (lane >> 4)*8;
        unsigned short u[8];
        #pragma unroll
        for (int e = 0; e < 8; e++) {
            int k = ks + e;
            float v = 0.f;
            if (row < 128)      v = qkv_w[row*64 + k];
            else if (row < 131) v = sG[(row-128)*64 + k];
            unsigned short h = f2bf(v);
            if (ver == 0) u[e] = h;
            else          u[e] = f2bf(v - bf2f(h));
        }
        unsigned* dst = (unsigned*)(ws + OFF_FRAG) + (ver*1152 + (nt*2+kb)*64 + lane)*4;
        dst[0] = (unsigned)u[0] | ((unsigned)u[1] << 16);
        dst[1] = (unsigned)u[2] | ((unsigned)u[3] << 16);
        dst[2] = (unsigned)u[4] | ((unsigned)u[5] << 16);
        dst[3] = (unsigned)u[6] | ((unsigned)u[7] << 16);
    }
}

// ---------------- k1: 4 tiles/block, reg-prefetch pipelined, MFMA proj+conv+Gram
// LDS (bytes):
//   XT   [0,10752)        84 rows x 128 B (x hi, granule-XOR swz)
//   QKH  [10752, 27136)   128 rows x 128 B (q/k post-conv bf16) — separate region
//   ZLDS [27136, 28144)   3 x 84 f32
#define XT    0
#define QKH   10752
#define ZLDS  27136
#define SMEM_BYTES 28160

__device__ __forceinline__ void load_item(const float* __restrict__ xb, int w0,
                                          bool safe, int i, uint4& out) {
    int j = i >> 5, chp = i & 31;
    int pos0 = w0 - 4 + 4*j;
    float4 a, c;
    if (safe || (unsigned)pos0 < (unsigned)Wd) {
        a = *(const float4*)(xb + (size_t)(2*chp)*Wd + pos0);
        c = *(const float4*)(xb + (size_t)(2*chp+1)*Wd + pos0);
    } else {
        a = (float4){0,0,0,0}; c = (float4){0,0,0,0};
    }
    out.x = pk2(a.x, c.x);
    out.y = pk2(a.y, c.y);
    out.z = pk2(a.z, c.z);
    out.w = pk2(a.w, c.w);
}
__device__ __forceinline__ void store_item(unsigned char* smem, int i, const uint4& v) {
    int j = i >> 5, chp = i & 31;
    const unsigned* pv = &v.x;
    #pragma unroll
    for (int e = 0; e < 4; e++) {
        int row = 4*j + e;
        int boff = row*128 + ((((chp>>2) ^ (row & 7)) << 4) | ((chp & 3) << 2));
        *(unsigned*)(smem + XT + boff) = pv[e];
    }
}

__global__ __launch_bounds__(256, 4) void k1_main(const float* __restrict__ x,
    const float* __restrict__ qkv_b, const float* __restrict__ dw_w,
    const float* __restrict__ dw_b, float* __restrict__ ws)
{
    __shared__ __align__(16) unsigned char smem[SMEM_BYTES];
    const int tid = threadIdx.x, lane = tid & 63, wv = tid >> 6;
    const int g = lane >> 4, lr = lane & 15;
    const int tg = blockIdx.x, b = blockIdx.y;
    const float* xb = x + (size_t)b * 64 * Wd;
    const uint4* fragbase = (const uint4*)(ws + OFF_FRAG);
    float* zlds = (float*)(smem + ZLDS);

    // per-row weight scalars (row = nt*16+lr, nt = wv + 4*nti), hoisted
    float bias_[2], tb_[2], t0_[2], t1_[2], t2_[2];
    #pragma unroll
    for (int nti = 0; nti < 2; nti++) {
        int row = (wv + nti*4)*16 + lr;
        bias_[nti] = qkv_b[row];
        tb_[nti] = dw_b[row];
        t0_[nti] = dw_w[row*9+3]; t1_[nti] = dw_w[row*9+4]; t2_[nti] = dw_w[row*9+5];
    }

    f32x4 sqk = (f32x4){0,0,0,0}, sqq = (f32x4){0,0,0,0}, skk = (f32x4){0,0,0,0};

    const bool has3 = (tid < 160);
    uint4 pf0, pf1, pf2;
    {   // prologue: stage-load tile (tg*4 + 0)
        bool safe0 = (tg != 0);
        load_item(xb, tg*256, safe0, tid, pf0);
        load_item(xb, tg*256, safe0, tid+256, pf1);
        if (has3) load_item(xb, tg*256, safe0, tid+512, pf2);
    }

    for (int t = 0; t < 4; ++t) {
        const int tile = tg*4 + t;
        const int w0 = tile*Ttile;
        const bool safe = (tile != 0) && (tile != 127);

        store_item(smem, tid, pf0);
        store_item(smem, tid+256, pf1);
        if (has3) store_item(smem, tid+512, pf2);
        __syncthreads();
        if (t < 3) {   // prefetch next tile; retires under GEMM+epilogue
            bool safen = ((tile+1) != 127);
            load_item(xb, w0+64, safen, tid, pf0);
            load_item(xb, w0+64, safen, tid+256, pf1);
            if (has3) load_item(xb, w0+64, safen, tid+512, pf2);
        }

        // ---- GEMM: C(80 slots x 131 W-rows) = Xhi^T @ W^T (W hi/lo 2-pass)
        f32x4 acc[2][5];
        f32x4 accz0 = (f32x4){0,0,0,0}, accz1 = (f32x4){0,0,0,0};
        #pragma unroll
        for (int i = 0; i < 2; i++)
            #pragma unroll
            for (int m = 0; m < 5; m++) acc[i][m] = (f32x4){0,0,0,0};

        #pragma unroll
        for (int kb = 0; kb < 2; kb++) {
            bf16x8 axh[5];
            #pragma unroll
            for (int mt = 0; mt < 5; mt++) {
                int row = mt*16 + lr + 3;
                int gran = (kb*4 + g) ^ (row & 7);
                axh[mt] = *(const bf16x8*)(smem + XT + row*128 + gran*16);
            }
            #pragma unroll
            for (int nti = 0; nti < 2; nti++) {
                int nt = wv + nti*4;
                bf16x8 bh = __builtin_bit_cast(bf16x8, fragbase[(nt*2+kb)*64 + lane]);
                bf16x8 bl = __builtin_bit_cast(bf16x8, fragbase[1152 + (nt*2+kb)*64 + lane]);
                #pragma unroll
                for (int mt = 0; mt < 5; mt++) {
                    acc[nti][mt] = __builtin_amdgcn_mfma_f32_16x16x32_bf16(axh[mt], bh, acc[nti][mt], 0,0,0);
                    acc[nti][mt] = __builtin_amdgcn_mfma_f32_16x16x32_bf16(axh[mt], bl, acc[nti][mt], 0,0,0);
                }
            }
            {   // z rows (nt=8): wave wv handles mt=wv; wave 0 additionally mt=4
                bf16x8 bzh = __builtin_bit_cast(bf16x8, fragbase[(16+kb)*64 + lane]);
                bf16x8 bzl = __builtin_bit_cast(bf16x8, fragbase[1152 + (16+kb)*64 + lane]);
                int rowz = wv*16 + lr + 3;
                int granz = (kb*4 + g) ^ (rowz & 7);
                bf16x8 azh = *(const bf16x8*)(smem + XT + rowz*128 + granz*16);
                accz0 = __builtin_amdgcn_mfma_f32_16x16x32_bf16(azh, bzh, accz0, 0,0,0);
                accz0 = __builtin_amdgcn_mfma_f32_16x16x32_bf16(azh, bzl, accz0, 0,0,0);
                if (wv == 0) {
                    accz1 = __builtin_amdgcn_mfma_f32_16x16x32_bf16(axh[4], bzh, accz1, 0,0,0);
                    accz1 = __builtin_amdgcn_mfma_f32_16x16x32_bf16(axh[4], bzl, accz1, 0,0,0);
                }
            }
        }

        // ---- epilogue q/k -> QKH (same-wave rows; no barrier needed before Gram)
        #pragma unroll
        for (int nti = 0; nti < 2; nti++) {
            int nt = wv + nti*4;
            int row = nt*16 + lr;
            float bias = bias_[nti], tb = tb_[nti];
            float t0 = t0_[nti], t1 = t1_[nti], t2 = t2_[nti];
            float4 v[5];
            #pragma unroll
            for (int mt = 0; mt < 5; mt++) {
                #pragma unroll
                for (int r = 0; r < 4; r++) {
                    float val = acc[nti][mt][r] + bias;
                    if (!safe) {
                        int pos = w0 - 1 + mt*16 + g*4 + r;
                        if (pos < 0 || pos >= Wd) val = 0.f;
                    }
                    ((float*)&v[mt])[r] = val;
                }
            }
            int src = (lane + 16) & 63;
            #pragma unroll
            for (int mt = 0; mt < 4; mt++) {
                float a0 = __shfl(v[mt].x,   src), b0 = __shfl(v[mt+1].x, src);
                float a1 = __shfl(v[mt].y,   src), b1 = __shfl(v[mt+1].y, src);
                float in4 = (lane < 48) ? a0 : b0;
                float in5 = (lane < 48) ? a1 : b1;
                float o0 = tb + t0*v[mt].x + t1*v[mt].y + t2*v[mt].z;
                float o1 = tb + t0*v[mt].y + t1*v[mt].z + t2*v[mt].w;
                float o2 = tb + t0*v[mt].z + t1*v[mt].w + t2*in4;
                float o3 = tb + t0*v[mt].w + t1*in4     + t2*in5;
                uint2 hw;
                hw.x = pk2(o0, o1);
                hw.y = pk2(o2, o3);
                int gran = (2*mt + (g>>1)) ^ (row & 7);
                int boff = row*128 + (gran << 4) + ((g & 1) << 3);
                *(uint2*)(smem + QKH + boff) = hw;
            }
        }
        // ---- epilogue z -> zlds
        if (lr < 3) {
            float4 vz0 = { accz0[0], accz0[1], accz0[2], accz0[3] };
            *(float4*)(zlds + lr*84 + wv*16 + g*4) = vz0;
            if (wv == 0) {
                float4 vz1 = { accz1[0], accz1[1], accz1[2], accz1[3] };
                *(float4*)(zlds + lr*84 + 64 + g*4) = vz1;
            }
        }
        __syncthreads();

        // ---- xseq (slots 0..65 <-> pos w0-1..w0+64)
        if (tid < 64) {
            float a = ws[OFF_BASE];
            #pragma unroll
            for (int j = 0; j < 3; j++) {
                int wg = w0 + tid + j - 1;
                a += zlds[j*84 + tid + j];
                if (wg >= 0 && wg < Wd) a += ws[OFF_H + j];
            }
            ws[OFF_XSEQ + (size_t)b*Wd + w0 + tid] = a;
        }

        // ---- Gram accumulate via MFMA (wave-owned QKH rows)
        {
            const int rq = wv*16 + lr;
            const int rk = 64 + wv*16 + lr;
            #pragma unroll
            for (int kb = 0; kb < 2; kb++) {
                int gran = (kb*4 + g) ^ (lr & 7);
                bf16x8 qh = *(const bf16x8*)(smem + QKH + rq*128 + gran*16);
                bf16x8 kh = *(const bf16x8*)(smem + QKH + rk*128 + gran*16);
                sqk = __builtin_amdgcn_mfma_f32_16x16x32_bf16(qh, kh, sqk, 0,0,0);
                sqq = __builtin_amdgcn_mfma_f32_16x16x32_bf16(qh, qh, sqq, 0,0,0);
                skk = __builtin_amdgcn_mfma_f32_16x16x32_bf16(kh, kh, skk, 0,0,0);
            }
        }
    }

    // ---- part write (once per block, 4 tiles accumulated)
    {
        float* pb = ws + OFF_PART + (size_t)(b*32 + tg)*640;
        int hh = lr >> 3, c2 = lr & 7;
        if (hh == (g >> 1)) {
            #pragma unroll
            for (int r = 0; r < 4; r++) {
                int c1 = (g & 1)*4 + r;
                pb[(2*wv + hh)*64 + c1*8 + c2] = sqk[r];
            }
        }
        if ((lr >> 2) == g) {
            int r = lr & 3;
            pb[512 + wv*16 + lr] = sqq[r];
            pb[576 + wv*16 + lr] = skk[r];
        }
    }
}

// ---------------- k23: role A (bx<160): reduce part -> S ; role B: MTL scalars
__device__ __forceinline__ float blk_reduce_256(float v, float* sc) {
    #pragma unroll
    for (int off = 32; off > 0; off >>= 1) v += __shfl_down(v, off, 64);
    __syncthreads();
    if ((threadIdx.x & 63) == 0) sc[threadIdx.x >> 6] = v;
    __syncthreads();
    return sc[0] + sc[1] + sc[2] + sc[3];
}

__global__ __launch_bounds__(256) void k23(const float* __restrict__ ws,
    const float* __restrict__ up_w, const float* __restrict__ up_b,
    const float* __restrict__ c2_w, const float* __restrict__ c2_b,
    const float* __restrict__ ln2_w, const float* __restrict__ ln2_b,
    const float* __restrict__ c4_w, const float* __restrict__ c4_b,
    const float* __restrict__ ln4_w, const float* __restrict__ ln4_b,
    const float* __restrict__ c6_w, const float* __restrict__ c6_b,
    const float* __restrict__ ln6_w, const float* __restrict__ ln6_b,
    float* __restrict__ wsS, float* __restrict__ wsM)
{
    __shared__ float ys[Wd];
    __shared__ float sc[4];
    int bx = blockIdx.x;
    if (bx < 160) {
        // S[b][idx] = sum over 32 tile-groups; idx chunked x5, depth halved x2
        int b = bx / 5, chunk = bx - (bx/5)*5;
        int idx = chunk*128 + (threadIdx.x & 127);
        int half = threadIdx.x >> 7;
        const float* part = ws + OFF_PART + (size_t)b*32*640 + idx;
        float s0 = 0.f, s1 = 0.f, s2 = 0.f, s3 = 0.f;
        int t0 = half*16;
        for (int t = t0; t < t0 + 16; t += 4) {
            s0 += part[(size_t)(t  )*640];
            s1 += part[(size_t)(t+1)*640];
            s2 += part[(size_t)(t+2)*640];
            s3 += part[(size_t)(t+3)*640];
        }
        float s = (s0 + s1) + (s2 + s3);
        if (half) ys[threadIdx.x & 127] = s;
        __syncthreads();
        if (!half) wsS[b*640 + idx] = s + ys[threadIdx.x];
        return;
    }
    int t2 = bx - 160;
    int br = t2 >> 5, b = t2 & 31;
    const float *cw, *lw, *lb; float cb; int K, lo;
    if (br == 0)      { cw = c2_w; cb = c2_b[0]; lw = ln2_w; lb = ln2_b; K = 2; lo = 0; }
    else if (br == 1) { cw = c4_w; cb = c4_b[0]; lw = ln4_w; lb = ln4_b; K = 4; lo = 1; }
    else              { cw = c6_w; cb = c6_b[0]; lw = ln6_w; lb = ln6_b; K = 6; lo = 2; }
    float uw = up_w[br], ub = up_b[br];
    const float* xr = ws + OFF_XSEQ + (size_t)b*Wd;

    float s = 0.f, s2 = 0.f;
    for (int w = threadIdx.x; w < Wd; w += 256) {
        float y = cb;
        for (int m = 0; m < K; m++) {
            int p = w + m - lo;
            if (p >= 0 && p < Wd) y += cw[m] * (uw*xr[p] + ub);
        }
        ys[w] = y; s += y; s2 += y*y;
    }
    float mu = blk_reduce_256(s, sc) * (1.f/Wd);
    __syncthreads();
    float Ey2 = blk_reduce_256(s2, sc) * (1.f/Wd);
    float var = fmaxf(Ey2 - mu*mu, 0.f);
    float inv = 1.f / sqrtf(var + 1e-5f);
    float se = 0.f;
    for (int w = threadIdx.x; w < Wd; w += 256) {
        float tt = (ys[w]-mu)*inv*lw[w] + lb[w];
        se += (tt > 0.f) ? tt : expm1f(tt);
    }
    float m = blk_reduce_256(se, sc) * (1.f/Wd);
    if (threadIdx.x == 0) wsM[b*3 + br] = m;
}

// ---------------- k4: norms -> softmax -> alpha/beta -> fold with proj -> E,F
__global__ __launch_bounds__(64) void k4_coeffs(const float* __restrict__ ws,
    const float* __restrict__ temperature,
    const float* __restrict__ mp_w, const float* __restrict__ mp_b,
    const float* __restrict__ up_w, const float* __restrict__ up_b,
    const float* __restrict__ proj_w, const float* __restrict__ proj_b,
    float* __restrict__ wsE, float* __restrict__ wsF)
{
    __shared__ float nk[64], alpha[64], beta[64];
    int b = blockIdx.x, t = threadIdx.x;
    const float* Sb = ws + OFF_S + b*640;
    float nq_t = fmaxf(sqrtf(Sb[512 + t]), 1e-12f);
    nk[t]      = fmaxf(sqrtf(Sb[576 + t]), 1e-12f);
    __syncthreads();
    int h = t >> 3;
    float temp = temperature[h];
    float lg[8];
    float mx = -1e30f;
    #pragma unroll
    for (int d = 0; d < 8; d++) {
        lg[d] = Sb[8*t + d] / (nq_t * nk[h*8 + d]) * temp;
        mx = fmaxf(mx, lg[d]);
    }
    float sum = 0.f;
    #pragma unroll
    for (int d = 0; d < 8; d++) { lg[d] = expf(lg[d] - mx); sum += lg[d]; }
    float a = 0.f, bb = 0.f;
    #pragma unroll
    for (int d = 0; d < 8; d++) {
        float at = lg[d] / sum;
        a  += at * mp_w[h*8 + d];
        bb += at * mp_b[h*8 + d];
    }
    alpha[t] = a; beta[t] = bb;
    __syncthreads();
    const float* wm = ws + OFF_M + b*3;
    float m2 = wm[0], m4 = wm[1], m6 = wm[2];
    float A = m2*up_w[0] + m4*up_w[1] + m6*up_w[2];
    float C = m2*up_b[0] + m4*up_b[1] + m6*up_b[2];
    float Pa = 0.f, Pb = 0.f;
    for (int c = 0; c < 64; c++) {
        float pw = proj_w[t*64 + c];
        Pa += pw * alpha[c];
        Pb += pw * beta[c];
    }
    wsE[b*64 + t] = A * Pa;
    wsF[b*64 + t] = C * Pa + Pb + proj_b[t];
}

// ---------------- k5: pure stream  out[b,o,w] = E[b,o]*xseq[b,w] + F[b,o]
__global__ __launch_bounds__(256) void k5_out(const float* __restrict__ ws,
                                              float* __restrict__ out)
{
    __shared__ float sE[64], sF[64];
    const int tid = threadIdx.x;
    const int chunk = blockIdx.x, b = blockIdx.y;
    if (tid < 64) {
        sE[tid] = ws[OFF_E + b*64 + tid];
        sF[tid] = ws[OFF_F + b*64 + tid];
    }
    __syncthreads();
    const float4* xs4 = (const float4*)(ws + OFF_XSEQ + (size_t)b*Wd);
    float4 xv = xs4[chunk*128 + (tid & 127)];
    int ohalf = tid >> 7;
    float4* ob = (float4*)out + (size_t)b*64*2048 + chunk*128 + (tid & 127);
    #pragma unroll 8
    for (int oo = 0; oo < 32; oo++) {
        int o = ohalf*32 + oo;
        float e = sE[o], f = sF[o];
        float4 r = { e*xv.x + f, e*xv.y + f, e*xv.z + f, e*xv.w + f };
        ob[(size_t)o*2048] = r;
    }
}

extern "C" void kernel_launch(void* const* d_in, const int* in_sizes, int n_in,
                              void* d_out, int out_size, void* d_ws, size_t ws_size,
                              hipStream_t stream) {
    const float* x      = (const float*)d_in[0];
    const float* qkv_w  = (const float*)d_in[1];
    const float* qkv_b  = (const float*)d_in[2];
    const float* dw_w   = (const float*)d_in[3];
    const float* dw_b   = (const float*)d_in[4];
    const float* proj_w = (const float*)d_in[5];
    const float* proj_b = (const float*)d_in[6];
    const float* temperature = (const float*)d_in[7];
    const float* sp_w   = (const float*)d_in[8];
    const float* sp_b   = (const float*)d_in[9];
    const float* up_w   = (const float*)d_in[10];
    const float* up_b   = (const float*)d_in[11];
    const float* c2_w   = (const float*)d_in[12];
    const float* c2_b   = (const float*)d_in[13];
    const float* ln2_w  = (const float*)d_in[14];
    const float* ln2_b  = (const float*)d_in[15];
    const float* c4_w   = (const float*)d_in[16];
    const float* c4_b   = (const float*)d_in[17];
    const float* ln4_w  = (const float*)d_in[18];
    const float* ln4_b  = (const float*)d_in[19];
    const float* c6_w   = (const float*)d_in[20];
    const float* c6_b   = (const float*)d_in[21];
    const float* ln6_w  = (const float*)d_in[22];
    const float* ln6_b  = (const float*)d_in[23];
    const float* mp_w   = (const float*)d_in[24];
    const float* mp_b   = (const float*)d_in[25];
    float* ws  = (float*)d_ws;
    float* out = (float*)d_out;

    k0_setup<<<1, 256, 0, stream>>>(qkv_w, qkv_b, dw_w, dw_b, sp_w, sp_b, ws);
    k1_main<<<dim3(32, 32), 256, 0, stream>>>(x, qkv_b, dw_w, dw_b, ws);
    k23<<<256, 256, 0, stream>>>(ws, up_w, up_b,
        c2_w, c2_b, ln2_w, ln2_b, c4_w, c4_b, ln4_w, ln4_b, c6_w, c6_b, ln6_w, ln6_b,
        ws + OFF_S, ws + OFF_M);
    k4_coeffs<<<32, 64, 0, stream>>>(ws, temperature, mp_w, mp_b,
        up_w, up_b, proj_w, proj_b, ws + OFF_E, ws + OFF_F);
    k5_out<<<dim3(16, 32), 256, 0, stream>>>(ws, out);
}

// Round 7
// 121.624 us; speedup vs baseline: 1.6965x; 1.6965x over previous
//
#include <hip/hip_runtime.h>
#include <hip/hip_bf16.h>
#include <math.h>

#define Wd 8192
#define Bd 32
#define Ttile 64

// ws layout (float offsets)
#define OFF_H    192                        // 3
#define OFF_BASE 195                        // 1
#define OFF_XSEQ 256                        // 32*8192
#define OFF_PART (256 + Bd*Wd)              // [b][64 tile-groups][640]
#define OFF_S    (OFF_PART + Bd*64*640)     // 32*640
#define OFF_M    (OFF_S + Bd*640)           // 32*3
#define OFF_E    (OFF_M + 96)               // 32*64
#define OFF_F    (OFF_E + Bd*64)            // 32*64
#define OFF_FRAG (OFF_F + Bd*64)            // 2 ver * 9 nt * 2 kb * 64 lane * uint4

typedef __attribute__((ext_vector_type(8))) short bf16x8;
typedef __attribute__((ext_vector_type(4))) float f32x4;

__device__ __forceinline__ unsigned short f2bf(float v) {
    return __builtin_bit_cast(unsigned short, __float2bfloat16(v));
}
__device__ __forceinline__ float bf2f(unsigned short h) {
    return __builtin_bit_cast(float, (unsigned)h << 16);
}
__device__ __forceinline__ unsigned pk2(float v0, float v1) {
    return (unsigned)f2bf(v0) | ((unsigned)f2bf(v1) << 16);
}

// ---------------- k0: 4 blocks; each computes G locally (cheap) and packs 9
// fragment chunks; block 0 also writes H/base.
__global__ __launch_bounds__(256) void k0_setup(const float* __restrict__ qkv_w,
                         const float* __restrict__ qkv_b,
                         const float* __restrict__ dw_w, const float* __restrict__ dw_b,
                         const float* __restrict__ sp_w, const float* __restrict__ sp_b,
                         float* __restrict__ ws)
{
    __shared__ float sw[64*64];   // qkv_w rows 128..191: sw[c*64+ch]
    __shared__ float sdw[192];    // dw_w[(128+c)*9+3+j] -> sdw[c*3+j]
    __shared__ float ssp[64];
    __shared__ float sqb[64];     // qkv_b[128+c]
    __shared__ float sdb[64];     // dw_b[128+c]
    __shared__ float sG[192];     // G[j*64+ch]
    int tid = threadIdx.x, bx = blockIdx.x;
    for (int i = tid; i < 4096; i += 256) sw[i] = qkv_w[128*64 + i];
    if (tid < 192) { int c = tid/3, j = tid - 3*c; sdw[tid] = dw_w[(128+c)*9 + 3 + j]; }
    if (tid < 64)  { ssp[tid] = sp_w[tid]; sqb[tid] = qkv_b[128+tid]; sdb[tid] = dw_b[128+tid]; }
    __syncthreads();
    if (tid < 192) {
        int j = tid >> 6, ch = tid & 63;
        float acc = 0.f;
        #pragma unroll 8
        for (int c = 0; c < 64; c++)
            acc += ssp[c] * sdw[c*3+j] * sw[c*64 + ch];
        sG[j*64 + ch] = acc;
    } else if (bx == 0 && tid < 195) {
        int j = tid - 192;
        float h = 0.f;
        #pragma unroll 8
        for (int c = 0; c < 64; c++)
            h += ssp[c] * sdw[c*3+j] * sqb[c];
        ws[OFF_H + j] = h;
    } else if (bx == 0 && tid == 195) {
        float base = sp_b[0];
        #pragma unroll 8
        for (int c = 0; c < 64; c++) base += ssp[c] * sdb[c];
        ws[OFF_BASE] = base;
    }
    __syncthreads();
    // pack chunks [bx*9, bx*9+9): item = (cidx, lane)
    for (int it = tid; it < 9*64; it += 256) {
        int lane = it & 63;
        int cidx = bx*9 + (it >> 6);
        int ver = cidx / 18;
        int rem = cidx - ver*18;
        int nt = rem >> 1, kb = rem & 1;
        int row = nt*16 + (lane & 15);
        int ks  = kb*32 + (lane >> 4)*8;
        unsigned short u[8];
        #pragma unroll
        for (int e = 0; e < 8; e++) {
            int k = ks + e;
            float v = 0.f;
            if (row < 128)      v = qkv_w[row*64 + k];
            else if (row < 131) v = sG[(row-128)*64 + k];
            unsigned short h = f2bf(v);
            if (ver == 0) u[e] = h;
            else          u[e] = f2bf(v - bf2f(h));
        }
        unsigned* dst = (unsigned*)(ws + OFF_FRAG) + (ver*1152 + (nt*2+kb)*64 + lane)*4;
        dst[0] = (unsigned)u[0] | ((unsigned)u[1] << 16);
        dst[1] = (unsigned)u[2] | ((unsigned)u[3] << 16);
        dst[2] = (unsigned)u[4] | ((unsigned)u[5] << 16);
        dst[3] = (unsigned)u[6] | ((unsigned)u[7] << 16);
    }
}

// ---------------- k1: 2 tiles/block, XT double-buffered, reg-prefetch pipeline
// LDS (bytes):
//   XT0  [0,10752)        84 rows x 128 B (x hi, granule-XOR swz)
//   XT1  [10752,21504)
//   QKH  [21504,37888)    128 rows x 128 B (q/k post-conv bf16)
//   ZLDS [37888,38896)    3 x 84 f32
#define XT0   0
#define XT1   10752
#define QKH   21504
#define ZLDS  37888
#define SMEM_BYTES 38912

__device__ __forceinline__ void load_pair(const float* __restrict__ xb, int w0,
                                          bool safe, int i, float4& a, float4& c) {
    int j = i >> 5, chp = i & 31;
    int pos0 = w0 - 4 + 4*j;
    if (safe || (unsigned)pos0 < (unsigned)Wd) {
        a = *(const float4*)(xb + (size_t)(2*chp)*Wd + pos0);
        c = *(const float4*)(xb + (size_t)(2*chp+1)*Wd + pos0);
    } else {
        a = (float4){0,0,0,0}; c = (float4){0,0,0,0};
    }
}
__device__ __forceinline__ void store_pair(unsigned char* base, int i,
                                           const float4& a, const float4& c) {
    int j = i >> 5, chp = i & 31;
    const float* pa = &a.x; const float* pc = &c.x;
    #pragma unroll
    for (int e = 0; e < 4; e++) {
        int row = 4*j + e;
        unsigned hw = pk2(pa[e], pc[e]);
        int boff = row*128 + ((((chp>>2) ^ (row & 7)) << 4) | ((chp & 3) << 2));
        *(unsigned*)(base + boff) = hw;
    }
}

__global__ __launch_bounds__(256) void k1_main(const float* __restrict__ x,
    const float* __restrict__ qkv_b, const float* __restrict__ dw_w,
    const float* __restrict__ dw_b, float* __restrict__ ws)
{
    __shared__ __align__(16) unsigned char smem[SMEM_BYTES];
    const int tid = threadIdx.x, lane = tid & 63, wv = tid >> 6;
    const int g = lane >> 4, lr = lane & 15;
    const int tg = blockIdx.x, b = blockIdx.y;
    const float* xb = x + (size_t)b * 64 * Wd;
    const uint4* fragbase = (const uint4*)(ws + OFF_FRAG);
    float* zlds = (float*)(smem + ZLDS);
    const bool has3 = (tid < 160);

    // hoisted per-row weight scalars (row = (wv+4*nti)*16+lr)
    float bias_[2], tb_[2], t0_[2], t1_[2], t2_[2];
    #pragma unroll
    for (int nti = 0; nti < 2; nti++) {
        int row = (wv + nti*4)*16 + lr;
        bias_[nti] = qkv_b[row];
        tb_[nti] = dw_b[row];
        t0_[nti] = dw_w[row*9+3]; t1_[nti] = dw_w[row*9+4]; t2_[nti] = dw_w[row*9+5];
    }

    f32x4 sqk = (f32x4){0,0,0,0}, sqq = (f32x4){0,0,0,0}, skk = (f32x4){0,0,0,0};

    float4 a0,c0,a1,c1,a2,c2;
    {   // prologue: stage tile 2tg into XT0
        int tile = 2*tg; int w0 = tile*Ttile; bool sf = (tile != 0);
        load_pair(xb, w0, sf, tid, a0, c0);
        load_pair(xb, w0, sf, tid+256, a1, c1);
        if (has3) load_pair(xb, w0, sf, tid+512, a2, c2);
        store_pair(smem+XT0, tid, a0, c0);
        store_pair(smem+XT0, tid+256, a1, c1);
        if (has3) store_pair(smem+XT0, tid+512, a2, c2);
    }
    __syncthreads();

    #pragma unroll
    for (int t = 0; t < 2; t++) {
        const int tile = 2*tg + t;
        const int w0 = tile*Ttile;
        const bool safe = (tile != 0) && (tile != 127);
        unsigned char* xtb = smem + (t ? XT1 : XT0);

        if (t == 1) __syncthreads();   // xseq(0) zlds reads done before epi(1) writes

        if (t == 0) {   // prefetch tile+1; retires under GEMM+epilogue
            bool sf = (tile+1 != 127);
            load_pair(xb, w0+64, sf, tid, a0, c0);
            load_pair(xb, w0+64, sf, tid+256, a1, c1);
            if (has3) load_pair(xb, w0+64, sf, tid+512, a2, c2);
        }

        // ---- GEMM: C(80 slots x 131 W-rows) = Xhi^T @ W^T (W hi/lo 2-pass)
        f32x4 acc[2][5];
        f32x4 accz0 = (f32x4){0,0,0,0}, accz1 = (f32x4){0,0,0,0};
        #pragma unroll
        for (int i = 0; i < 2; i++)
            #pragma unroll
            for (int m = 0; m < 5; m++) acc[i][m] = (f32x4){0,0,0,0};

        #pragma unroll
        for (int kb = 0; kb < 2; kb++) {
            bf16x8 axh[5];
            #pragma unroll
            for (int mt = 0; mt < 5; mt++) {
                int row = mt*16 + lr + 3;
                int gran = (kb*4 + g) ^ (row & 7);
                axh[mt] = *(const bf16x8*)(xtb + row*128 + gran*16);
            }
            #pragma unroll
            for (int nti = 0; nti < 2; nti++) {
                int nt = wv + nti*4;
                bf16x8 bh = __builtin_bit_cast(bf16x8, fragbase[(nt*2+kb)*64 + lane]);
                bf16x8 bl = __builtin_bit_cast(bf16x8, fragbase[1152 + (nt*2+kb)*64 + lane]);
                #pragma unroll
                for (int mt = 0; mt < 5; mt++) {
                    acc[nti][mt] = __builtin_amdgcn_mfma_f32_16x16x32_bf16(axh[mt], bh, acc[nti][mt], 0,0,0);
                    acc[nti][mt] = __builtin_amdgcn_mfma_f32_16x16x32_bf16(axh[mt], bl, acc[nti][mt], 0,0,0);
                }
            }
            {   // z rows (nt=8): wave wv does mt=wv; wave 0 additionally mt=4
                bf16x8 bzh = __builtin_bit_cast(bf16x8, fragbase[(16+kb)*64 + lane]);
                bf16x8 bzl = __builtin_bit_cast(bf16x8, fragbase[1152 + (16+kb)*64 + lane]);
                int rowz = wv*16 + lr + 3;
                int granz = (kb*4 + g) ^ (rowz & 7);
                bf16x8 azh = *(const bf16x8*)(xtb + rowz*128 + granz*16);
                accz0 = __builtin_amdgcn_mfma_f32_16x16x32_bf16(azh, bzh, accz0, 0,0,0);
                accz0 = __builtin_amdgcn_mfma_f32_16x16x32_bf16(azh, bzl, accz0, 0,0,0);
                if (wv == 0) {
                    accz1 = __builtin_amdgcn_mfma_f32_16x16x32_bf16(axh[4], bzh, accz1, 0,0,0);
                    accz1 = __builtin_amdgcn_mfma_f32_16x16x32_bf16(axh[4], bzl, accz1, 0,0,0);
                }
            }
        }

        // ---- epilogue q/k -> QKH (same-wave rows)
        #pragma unroll
        for (int nti = 0; nti < 2; nti++) {
            int nt = wv + nti*4;
            int row = nt*16 + lr;
            float bias = bias_[nti], tb = tb_[nti];
            float t0 = t0_[nti], t1 = t1_[nti], t2 = t2_[nti];
            float4 v[5];
            #pragma unroll
            for (int mt = 0; mt < 5; mt++) {
                #pragma unroll
                for (int r = 0; r < 4; r++) {
                    float val = acc[nti][mt][r] + bias;
                    if (!safe) {
                        int pos = w0 - 1 + mt*16 + g*4 + r;
                        if (pos < 0 || pos >= Wd) val = 0.f;
                    }
                    ((float*)&v[mt])[r] = val;
                }
            }
            int src = (lane + 16) & 63;
            #pragma unroll
            for (int mt = 0; mt < 4; mt++) {
                float sa0 = __shfl(v[mt].x,   src), sb0 = __shfl(v[mt+1].x, src);
                float sa1 = __shfl(v[mt].y,   src), sb1 = __shfl(v[mt+1].y, src);
                float in4 = (lane < 48) ? sa0 : sb0;
                float in5 = (lane < 48) ? sa1 : sb1;
                float o0 = tb + t0*v[mt].x + t1*v[mt].y + t2*v[mt].z;
                float o1 = tb + t0*v[mt].y + t1*v[mt].z + t2*v[mt].w;
                float o2 = tb + t0*v[mt].z + t1*v[mt].w + t2*in4;
                float o3 = tb + t0*v[mt].w + t1*in4     + t2*in5;
                uint2 hw;
                hw.x = pk2(o0, o1);
                hw.y = pk2(o2, o3);
                int gran = (2*mt + (g>>1)) ^ (row & 7);
                int boff = row*128 + (gran << 4) + ((g & 1) << 3);
                *(uint2*)(smem + QKH + boff) = hw;
            }
        }
        // ---- epilogue z -> zlds
        if (lr < 3) {
            float4 vz0 = { accz0[0], accz0[1], accz0[2], accz0[3] };
            *(float4*)(zlds + lr*84 + wv*16 + g*4) = vz0;
            if (wv == 0) {
                float4 vz1 = { accz1[0], accz1[1], accz1[2], accz1[3] };
                *(float4*)(zlds + lr*84 + 64 + g*4) = vz1;
            }
        }
        if (t == 0) {   // store prefetched tile into XT1
            store_pair(smem+XT1, tid, a0, c0);
            store_pair(smem+XT1, tid+256, a1, c1);
            if (has3) store_pair(smem+XT1, tid+512, a2, c2);
        }
        __syncthreads();   // zlds visible; XT1 ready for next GEMM

        // ---- xseq (slots 0..65 <-> pos w0-1..w0+64)
        if (tid < 64) {
            float a = ws[OFF_BASE];
            #pragma unroll
            for (int j = 0; j < 3; j++) {
                int wg = w0 + tid + j - 1;
                a += zlds[j*84 + tid + j];
                if (wg >= 0 && wg < Wd) a += ws[OFF_H + j];
            }
            ws[OFF_XSEQ + (size_t)b*Wd + w0 + tid] = a;
        }

        // ---- Gram accumulate via MFMA (wave-owned QKH rows)
        {
            const int rq = wv*16 + lr;
            const int rk = 64 + wv*16 + lr;
            #pragma unroll
            for (int kb = 0; kb < 2; kb++) {
                int gran = (kb*4 + g) ^ (lr & 7);
                bf16x8 qh = *(const bf16x8*)(smem + QKH + rq*128 + gran*16);
                bf16x8 kh = *(const bf16x8*)(smem + QKH + rk*128 + gran*16);
                sqk = __builtin_amdgcn_mfma_f32_16x16x32_bf16(qh, kh, sqk, 0,0,0);
                sqq = __builtin_amdgcn_mfma_f32_16x16x32_bf16(qh, qh, sqq, 0,0,0);
                skk = __builtin_amdgcn_mfma_f32_16x16x32_bf16(kh, kh, skk, 0,0,0);
            }
        }
    }

    // ---- part write (once per block, 2 tiles accumulated)
    {
        float* pb = ws + OFF_PART + (size_t)(b*64 + tg)*640;
        int hh = lr >> 3, c2 = lr & 7;
        if (hh == (g >> 1)) {
            #pragma unroll
            for (int r = 0; r < 4; r++) {
                int c1 = (g & 1)*4 + r;
                pb[(2*wv + hh)*64 + c1*8 + c2] = sqk[r];
            }
        }
        if ((lr >> 2) == g) {
            int r = lr & 3;
            pb[512 + wv*16 + lr] = sqq[r];
            pb[576 + wv*16 + lr] = skk[r];
        }
    }
}

// ---------------- k23: role A (bx<160): reduce part -> S ; role B: MTL scalars
__device__ __forceinline__ float blk_reduce_256(float v, float* sc) {
    #pragma unroll
    for (int off = 32; off > 0; off >>= 1) v += __shfl_down(v, off, 64);
    __syncthreads();
    if ((threadIdx.x & 63) == 0) sc[threadIdx.x >> 6] = v;
    __syncthreads();
    return sc[0] + sc[1] + sc[2] + sc[3];
}

__global__ __launch_bounds__(256) void k23(const float* __restrict__ ws,
    const float* __restrict__ up_w, const float* __restrict__ up_b,
    const float* __restrict__ c2_w, const float* __restrict__ c2_b,
    const float* __restrict__ ln2_w, const float* __restrict__ ln2_b,
    const float* __restrict__ c4_w, const float* __restrict__ c4_b,
    const float* __restrict__ ln4_w, const float* __restrict__ ln4_b,
    const float* __restrict__ c6_w, const float* __restrict__ c6_b,
    const float* __restrict__ ln6_w, const float* __restrict__ ln6_b,
    float* __restrict__ wsS, float* __restrict__ wsM)
{
    __shared__ float ys[Wd];
    __shared__ float sc[4];
    int bx = blockIdx.x;
    if (bx < 160) {
        // S[b][idx] = sum over 64 tile-groups; idx chunked x5, depth halved x2
        int b = bx / 5, chunk = bx - (bx/5)*5;
        int idx = chunk*128 + (threadIdx.x & 127);
        int half = threadIdx.x >> 7;
        const float* part = ws + OFF_PART + (size_t)b*64*640 + idx;
        float s0 = 0.f, s1 = 0.f, s2 = 0.f, s3 = 0.f;
        int t0 = half*32;
        for (int t = t0; t < t0 + 32; t += 4) {
            s0 += part[(size_t)(t  )*640];
            s1 += part[(size_t)(t+1)*640];
            s2 += part[(size_t)(t+2)*640];
            s3 += part[(size_t)(t+3)*640];
        }
        float s = (s0 + s1) + (s2 + s3);
        if (half) ys[threadIdx.x & 127] = s;
        __syncthreads();
        if (!half) wsS[b*640 + idx] = s + ys[threadIdx.x];
        return;
    }
    int t2 = bx - 160;
    int br = t2 >> 5, b = t2 & 31;
    const float *cw, *lw, *lb; float cb; int K, lo;
    if (br == 0)      { cw = c2_w; cb = c2_b[0]; lw = ln2_w; lb = ln2_b; K = 2; lo = 0; }
    else if (br == 1) { cw = c4_w; cb = c4_b[0]; lw = ln4_w; lb = ln4_b; K = 4; lo = 1; }
    else              { cw = c6_w; cb = c6_b[0]; lw = ln6_w; lb = ln6_b; K = 6; lo = 2; }
    float uw = up_w[br], ub = up_b[br];
    const float* xr = ws + OFF_XSEQ + (size_t)b*Wd;

    float s = 0.f, s2 = 0.f;
    for (int w = threadIdx.x; w < Wd; w += 256) {
        float y = cb;
        for (int m = 0; m < K; m++) {
            int p = w + m - lo;
            if (p >= 0 && p < Wd) y += cw[m] * (uw*xr[p] + ub);
        }
        ys[w] = y; s += y; s2 += y*y;
    }
    float mu = blk_reduce_256(s, sc) * (1.f/Wd);
    __syncthreads();
    float Ey2 = blk_reduce_256(s2, sc) * (1.f/Wd);
    float var = fmaxf(Ey2 - mu*mu, 0.f);
    float inv = 1.f / sqrtf(var + 1e-5f);
    float se = 0.f;
    for (int w = threadIdx.x; w < Wd; w += 256) {
        float tt = (ys[w]-mu)*inv*lw[w] + lb[w];
        se += (tt > 0.f) ? tt : expm1f(tt);
    }
    float m = blk_reduce_256(se, sc) * (1.f/Wd);
    if (threadIdx.x == 0) wsM[b*3 + br] = m;
}

// ---------------- k4: norms -> softmax -> alpha/beta -> fold with proj -> E,F
__global__ __launch_bounds__(64) void k4_coeffs(const float* __restrict__ ws,
    const float* __restrict__ temperature,
    const float* __restrict__ mp_w, const float* __restrict__ mp_b,
    const float* __restrict__ up_w, const float* __restrict__ up_b,
    const float* __restrict__ proj_w, const float* __restrict__ proj_b,
    float* __restrict__ wsE, float* __restrict__ wsF)
{
    __shared__ float nk[64], alpha[64], beta[64];
    int b = blockIdx.x, t = threadIdx.x;
    const float* Sb = ws + OFF_S + b*640;
    float nq_t = fmaxf(sqrtf(Sb[512 + t]), 1e-12f);
    nk[t]      = fmaxf(sqrtf(Sb[576 + t]), 1e-12f);
    __syncthreads();
    int h = t >> 3;
    float temp = temperature[h];
    float lg[8];
    float mx = -1e30f;
    #pragma unroll
    for (int d = 0; d < 8; d++) {
        lg[d] = Sb[8*t + d] / (nq_t * nk[h*8 + d]) * temp;
        mx = fmaxf(mx, lg[d]);
    }
    float sum = 0.f;
    #pragma unroll
    for (int d = 0; d < 8; d++) { lg[d] = expf(lg[d] - mx); sum += lg[d]; }
    float a = 0.f, bb = 0.f;
    #pragma unroll
    for (int d = 0; d < 8; d++) {
        float at = lg[d] / sum;
        a  += at * mp_w[h*8 + d];
        bb += at * mp_b[h*8 + d];
    }
    alpha[t] = a; beta[t] = bb;
    __syncthreads();
    const float* wm = ws + OFF_M + b*3;
    float m2 = wm[0], m4 = wm[1], m6 = wm[2];
    float A = m2*up_w[0] + m4*up_w[1] + m6*up_w[2];
    float C = m2*up_b[0] + m4*up_b[1] + m6*up_b[2];
    float Pa = 0.f, Pb = 0.f;
    for (int c = 0; c < 64; c++) {
        float pw = proj_w[t*64 + c];
        Pa += pw * alpha[c];
        Pb += pw * beta[c];
    }
    wsE[b*64 + t] = A * Pa;
    wsF[b*64 + t] = C * Pa + Pb + proj_b[t];
}

// ---------------- k5: pure stream  out[b,o,w] = E[b,o]*xseq[b,w] + F[b,o]
__global__ __launch_bounds__(256) void k5_out(const float* __restrict__ ws,
                                              float* __restrict__ out)
{
    __shared__ float sE[64], sF[64];
    const int tid = threadIdx.x;
    const int chunk = blockIdx.x, b = blockIdx.y;
    if (tid < 64) {
        sE[tid] = ws[OFF_E + b*64 + tid];
        sF[tid] = ws[OFF_F + b*64 + tid];
    }
    __syncthreads();
    const float4* xs4 = (const float4*)(ws + OFF_XSEQ + (size_t)b*Wd);
    float4 xv = xs4[chunk*128 + (tid & 127)];
    int ohalf = tid >> 7;
    float4* ob = (float4*)out + (size_t)b*64*2048 + chunk*128 + (tid & 127);
    #pragma unroll 8
    for (int oo = 0; oo < 32; oo++) {
        int o = ohalf*32 + oo;
        float e = sE[o], f = sF[o];
        float4 r = { e*xv.x + f, e*xv.y + f, e*xv.z + f, e*xv.w + f };
        ob[(size_t)o*2048] = r;
    }
}

extern "C" void kernel_launch(void* const* d_in, const int* in_sizes, int n_in,
                              void* d_out, int out_size, void* d_ws, size_t ws_size,
                              hipStream_t stream) {
    const float* x      = (const float*)d_in[0];
    const float* qkv_w  = (const float*)d_in[1];
    const float* qkv_b  = (const float*)d_in[2];
    const float* dw_w   = (const float*)d_in[3];
    const float* dw_b   = (const float*)d_in[4];
    const float* proj_w = (const float*)d_in[5];
    const float* proj_b = (const float*)d_in[6];
    const float* temperature = (const float*)d_in[7];
    const float* sp_w   = (const float*)d_in[8];
    const float* sp_b   = (const float*)d_in[9];
    const float* up_w   = (const float*)d_in[10];
    const float* up_b   = (const float*)d_in[11];
    const float* c2_w   = (const float*)d_in[12];
    const float* c2_b   = (const float*)d_in[13];
    const float* ln2_w  = (const float*)d_in[14];
    const float* ln2_b  = (const float*)d_in[15];
    const float* c4_w   = (const float*)d_in[16];
    const float* c4_b   = (const float*)d_in[17];
    const float* ln4_w  = (const float*)d_in[18];
    const float* ln4_b  = (const float*)d_in[19];
    const float* c6_w   = (const float*)d_in[20];
    const float* c6_b   = (const float*)d_in[21];
    const float* ln6_w  = (const float*)d_in[22];
    const float* ln6_b  = (const float*)d_in[23];
    const float* mp_w   = (const float*)d_in[24];
    const float* mp_b   = (const float*)d_in[25];
    float* ws  = (float*)d_ws;
    float* out = (float*)d_out;

    k0_setup<<<4, 256, 0, stream>>>(qkv_w, qkv_b, dw_w, dw_b, sp_w, sp_b, ws);
    k1_main<<<dim3(64, 32), 256, 0, stream>>>(x, qkv_b, dw_w, dw_b, ws);
    k23<<<256, 256, 0, stream>>>(ws, up_w, up_b,
        c2_w, c2_b, ln2_w, ln2_b, c4_w, c4_b, ln4_w, ln4_b, c6_w, c6_b, ln6_w, ln6_b,
        ws + OFF_S, ws + OFF_M);
    k4_coeffs<<<32, 64, 0, stream>>>(ws, temperature, mp_w, mp_b,
        up_w, up_b, proj_w, proj_b, ws + OFF_E, ws + OFF_F);
    k5_out<<<dim3(16, 32), 256, 0, stream>>>(ws, out);
}